// Round 9
// baseline (123.835 us; speedup 1.0000x reference)
//
#include <hip/hip_runtime.h>
#include <math.h>
#include <float.h>

// Problem constants (from the reference)
#define NN 4096
#define DD 512
#define PP 8
#define QQ 32
#define NB_TOT 40
#define NPW 10                     // neighbors per wave (4 waves x 10 = 40)
constexpr float MARGIN = 1.0f;
constexpr float L2W    = 0.005f;
constexpr float EPS    = 1e-6f;

typedef _Float16 half8 __attribute__((ext_vector_type(8)));

// ws layout (floats):
//   [0, NN*DD/2)             fp16 batch copy (4 MB, NN*DD halves)
//   [NN*DD/2, +NN)           per-row fp32 norms
#define WS_NORM (NN * DD / 2)

__device__ inline float wave_reduce_sum(float v) {
    v += __shfl_xor(v, 32, 64);
    v += __shfl_xor(v, 16, 64);
    v += __shfl_xor(v,  8, 64);
    v += __shfl_xor(v,  4, 64);
    v += __shfl_xor(v,  2, 64);
    v += __shfl_xor(v,  1, 64);
    return v;
}

__device__ inline float wave_reduce_max(float v) {
    v = fmaxf(v, __shfl_xor(v, 32, 64));
    v = fmaxf(v, __shfl_xor(v, 16, 64));
    v = fmaxf(v, __shfl_xor(v,  8, 64));
    v = fmaxf(v, __shfl_xor(v,  4, 64));
    v = fmaxf(v, __shfl_xor(v,  2, 64));
    v = fmaxf(v, __shfl_xor(v,  1, 64));
    return v;
}

// One wave per row: read 2KB fp32 (coalesced), write 1KB fp16 (coalesced),
// exact fp32 row norm. Also zeroes d_out (dist kernel accumulates into it).
__global__ __launch_bounds__(256) void convert_kernel(
    const float4* __restrict__ batch4,   // [NN*128]
    half8*        __restrict__ hb,       // [NN*64]
    float*        __restrict__ norms,    // [NN]
    float*        __restrict__ out)
{
    const int row  = blockIdx.x * 4 + (threadIdx.x >> 6);
    const int lane = threadIdx.x & 63;

    const float4 v0 = batch4[row * 128 + lane * 2];
    const float4 v1 = batch4[row * 128 + lane * 2 + 1];

    half8 h;
    h[0] = (_Float16)v0.x; h[1] = (_Float16)v0.y;
    h[2] = (_Float16)v0.z; h[3] = (_Float16)v0.w;
    h[4] = (_Float16)v1.x; h[5] = (_Float16)v1.y;
    h[6] = (_Float16)v1.z; h[7] = (_Float16)v1.w;
    hb[row * 64 + lane] = h;

    float s = v0.x*v0.x + v0.y*v0.y + v0.z*v0.z + v0.w*v0.w
            + v1.x*v1.x + v1.y*v1.y + v1.z*v1.z + v1.w*v1.w;
    s = wave_reduce_sum(s);
    if (lane == 0) norms[row] = sqrtf(s);
    if (blockIdx.x == 0 && threadIdx.x == 0) out[0] = 0.0f;
}

// One block per anchor; 4 waves x 10 neighbors (EXACT round-7 structure:
// this dataflow is what makes the compiler keep all 10 half8 row-requests
// in flight — do not perturb). Gather source is the 4 MB fp16 batch
// (L2-resident per XCD). Epilogue fused; one atomicAdd per block.
__global__ __launch_bounds__(256) void dist_kernel(
    const half8* __restrict__ hb,
    const int*   __restrict__ anchors,
    const int*   __restrict__ pos_idx,
    const int*   __restrict__ neg_idx,
    const float* __restrict__ norms,
    float*       __restrict__ out)
{
    const int i    = blockIdx.x;
    const int tid  = threadIdx.x;
    const int lane = tid & 63;
    const int wave = tid >> 6;            // 0..3
    const int jb   = wave * NPW;

    __shared__ float dist[NB_TOT];

    // ---- anchor row (one request), fp32 + eps ----
    const int arow = anchors[i];
    const half8 ah = hb[(size_t)arow * 64 + lane];
    float a[8];
    #pragma unroll
    for (int k = 0; k < 8; ++k) a[k] = (float)ah[k] + EPS;

    // ---- this wave's 10 neighbor indices (wave-uniform scalar loads) ----
    int idxs[NPW];
    #pragma unroll
    for (int t = 0; t < NPW; ++t) {
        const int j = jb + t;
        idxs[t] = (j < PP) ? pos_idx[i * PP + j] : neg_idx[i * QQ + (j - PP)];
    }

    // ---- all 10 row requests in flight ----
    half8 bh[NPW];
    #pragma unroll
    for (int t = 0; t < NPW; ++t)
        bh[t] = hb[(size_t)idxs[t] * 64 + lane];

    // ---- squared distances in fp32 ----
    float s[NPW];
    #pragma unroll
    for (int t = 0; t < NPW; ++t) {
        float acc = 0.0f;
        #pragma unroll
        for (int k = 0; k < 8; ++k) {
            const float d = a[k] - (float)bh[t][k];
            acc = fmaf(d, d, acc);
        }
        s[t] = acc;
    }

    // ---- 10 independent shuffle-reduce chains ----
    #pragma unroll
    for (int t = 0; t < NPW; ++t) s[t] = wave_reduce_sum(s[t]);

    // ---- lanes 0..9 store the 10 distances ----
    float v = s[0];
    #pragma unroll
    for (int t = 1; t < NPW; ++t) v = (lane == t) ? s[t] : v;
    if (lane < NPW) dist[jb + lane] = sqrtf(v);

    __syncthreads();

    // ---- wave-parallel logsumexp epilogue (lanes 0..39 of wave 0) ----
    if (wave == 0) {
        const float d = (lane < NB_TOT) ? dist[lane] : 0.0f;

        const bool pact = (lane < PP);
        const float pm = wave_reduce_max(pact ? d : -FLT_MAX);
        const float ps = wave_reduce_sum(pact ? expf(d - pm) : 0.0f);
        const float pos_term = pm + logf(ps);

        const bool nact = (lane >= PP) && (lane < NB_TOT);
        const float nv = MARGIN - d;
        const float nm = wave_reduce_max(nact ? nv : -FLT_MAX);
        const float ns = wave_reduce_sum(nact ? expf(nv - nm) : 0.0f);
        const float neg_term = nm + logf(ns);

        if (lane == 0) {
            const float val = fmaxf(0.0f, pos_term + neg_term) + L2W * norms[i];
            atomicAdd(out, val * (1.0f / (float)NN));
        }
    }
}

extern "C" void kernel_launch(void* const* d_in, const int* in_sizes, int n_in,
                              void* d_out, int out_size, void* d_ws, size_t ws_size,
                              hipStream_t stream) {
    const float* batch   = (const float*)d_in[0];
    const int*   anchors = (const int*)d_in[1];
    const int*   pos_idx = (const int*)d_in[2];
    const int*   neg_idx = (const int*)d_in[3];
    float*       wsf     = (float*)d_ws;
    float*       out     = (float*)d_out;

    half8* hb    = (half8*)wsf;
    float* norms = wsf + WS_NORM;

    convert_kernel<<<NN / 4, 256, 0, stream>>>((const float4*)batch, hb, norms, out);
    dist_kernel<<<NN, 256, 0, stream>>>(hb, anchors, pos_idx, neg_idx, norms, out);
}

// Round 10
// 83.289 us; speedup vs baseline: 1.4868x; 1.4868x over previous
//
#include <hip/hip_runtime.h>
#include <math.h>
#include <float.h>

// Problem constants (from the reference)
#define NN 4096
#define DD 512
#define PP 8
#define QQ 32
#define NB_TOT 40
#define NPW 10                     // neighbors per wave (4 waves x 10 = 40)
constexpr float MARGIN = 1.0f;
constexpr float L2W    = 0.005f;
constexpr float EPS    = 1e-6f;

typedef _Float16 half8 __attribute__((ext_vector_type(8)));

// ws layout (floats):
//   [0, NN*DD/2)             fp16 batch copy (4 MB, NN*DD halves)
//   [NN*DD/2, +NN)           per-row fp32 norms
//   [NN*DD/2+NN, +NN)        per-anchor results
#define WS_NORM (NN * DD / 2)
#define WS_RES  (WS_NORM + NN)

__device__ inline float wave_reduce_sum(float v) {
    v += __shfl_xor(v, 32, 64);
    v += __shfl_xor(v, 16, 64);
    v += __shfl_xor(v,  8, 64);
    v += __shfl_xor(v,  4, 64);
    v += __shfl_xor(v,  2, 64);
    v += __shfl_xor(v,  1, 64);
    return v;
}

__device__ inline float wave_reduce_max(float v) {
    v = fmaxf(v, __shfl_xor(v, 32, 64));
    v = fmaxf(v, __shfl_xor(v, 16, 64));
    v = fmaxf(v, __shfl_xor(v,  8, 64));
    v = fmaxf(v, __shfl_xor(v,  4, 64));
    v = fmaxf(v, __shfl_xor(v,  2, 64));
    v = fmaxf(v, __shfl_xor(v,  1, 64));
    return v;
}

// One wave per row: read 2KB fp32 (coalesced), write 1KB fp16 (coalesced),
// and compute the exact fp32 row norm. 4 rows per 256-thread block.
__global__ __launch_bounds__(256) void convert_kernel(
    const float4* __restrict__ batch4,   // [NN*128]
    half8*        __restrict__ hb,       // [NN*64]
    float*        __restrict__ norms)    // [NN]
{
    const int row  = blockIdx.x * 4 + (threadIdx.x >> 6);
    const int lane = threadIdx.x & 63;

    const float4 v0 = batch4[row * 128 + lane * 2];
    const float4 v1 = batch4[row * 128 + lane * 2 + 1];

    half8 h;
    h[0] = (_Float16)v0.x; h[1] = (_Float16)v0.y;
    h[2] = (_Float16)v0.z; h[3] = (_Float16)v0.w;
    h[4] = (_Float16)v1.x; h[5] = (_Float16)v1.y;
    h[6] = (_Float16)v1.z; h[7] = (_Float16)v1.w;
    hb[row * 64 + lane] = h;

    float s = v0.x*v0.x + v0.y*v0.y + v0.z*v0.z + v0.w*v0.w
            + v1.x*v1.x + v1.y*v1.y + v1.z*v1.z + v1.w*v1.w;
    s = wave_reduce_sum(s);
    if (lane == 0) norms[row] = sqrtf(s);
}

// One block per anchor; 4 waves x 10 neighbors (round-7 structure, the proven
// fast config). The sched_barrier after the gather cluster PINS the
// all-10-loads-in-flight schedule (R8/R9 showed the compiler otherwise
// collapses to a 28-VGPR serialized form, 3x slower). Gather source is the
// 4 MB fp16 batch (L2-resident per XCD). Distances fp32; eps pre-folded.
__global__ __launch_bounds__(256) void dist_kernel(
    const half8* __restrict__ hb,
    const int*   __restrict__ anchors,
    const int*   __restrict__ pos_idx,
    const int*   __restrict__ neg_idx,
    const float* __restrict__ norms,
    float*       __restrict__ res)
{
    const int i    = blockIdx.x;
    const int tid  = threadIdx.x;
    const int lane = tid & 63;
    const int wave = tid >> 6;            // 0..3
    const int jb   = wave * NPW;

    __shared__ float dist[NB_TOT];

    // ---- anchor row (one request), fp32 + eps ----
    const int arow = anchors[i];
    const half8 ah = hb[(size_t)arow * 64 + lane];
    float a[8];
    #pragma unroll
    for (int k = 0; k < 8; ++k) a[k] = (float)ah[k] + EPS;

    // ---- this wave's 10 neighbor indices (wave-uniform scalar loads) ----
    int idxs[NPW];
    #pragma unroll
    for (int t = 0; t < NPW; ++t) {
        const int j = jb + t;
        idxs[t] = (j < PP) ? pos_idx[i * PP + j] : neg_idx[i * QQ + (j - PP)];
    }

    // ---- all 10 row requests issued before ANY compute (pinned) ----
    half8 bh[NPW];
    #pragma unroll
    for (int t = 0; t < NPW; ++t)
        bh[t] = hb[(size_t)idxs[t] * 64 + lane];
    __builtin_amdgcn_sched_barrier(0);    // do not sink loads past this point

    // ---- squared distances in fp32 ----
    float s[NPW];
    #pragma unroll
    for (int t = 0; t < NPW; ++t) {
        float acc = 0.0f;
        #pragma unroll
        for (int k = 0; k < 8; ++k) {
            const float d = a[k] - (float)bh[t][k];
            acc = fmaf(d, d, acc);
        }
        s[t] = acc;
    }

    // ---- 10 independent shuffle-reduce chains ----
    #pragma unroll
    for (int t = 0; t < NPW; ++t) s[t] = wave_reduce_sum(s[t]);

    // ---- lanes 0..9 store the 10 distances ----
    float v = s[0];
    #pragma unroll
    for (int t = 1; t < NPW; ++t) v = (lane == t) ? s[t] : v;
    if (lane < NPW) dist[jb + lane] = sqrtf(v);

    __syncthreads();

    // ---- wave-parallel logsumexp epilogue (lanes 0..39 of wave 0) ----
    if (wave == 0) {
        const float d = (lane < NB_TOT) ? dist[lane] : 0.0f;

        const bool pact = (lane < PP);
        const float pm = wave_reduce_max(pact ? d : -FLT_MAX);
        const float ps = wave_reduce_sum(pact ? expf(d - pm) : 0.0f);
        const float pos_term = pm + logf(ps);

        const bool nact = (lane >= PP) && (lane < NB_TOT);
        const float nv = MARGIN - d;
        const float nm = wave_reduce_max(nact ? nv : -FLT_MAX);
        const float ns = wave_reduce_sum(nact ? expf(nv - nm) : 0.0f);
        const float neg_term = nm + logf(ns);

        if (lane == 0)
            res[i] = fmaxf(0.0f, pos_term + neg_term) + L2W * norms[i];
    }
}

// Single-block final reduction: out = mean(res[0..N))
__global__ __launch_bounds__(256) void reduce_kernel(
    const float* __restrict__ res, float* __restrict__ out)
{
    const int tid  = threadIdx.x;
    const int lane = tid & 63;
    const int wave = tid >> 6;

    const float4* __restrict__ w4 = reinterpret_cast<const float4*>(res);
    float s = 0.0f;
    #pragma unroll
    for (int k = 0; k < 4; ++k) {          // 1024 float4 total
        const float4 v = w4[tid + 256 * k];
        s += v.x + v.y + v.z + v.w;
    }
    s = wave_reduce_sum(s);

    __shared__ float part[4];
    if (lane == 0) part[wave] = s;
    __syncthreads();
    if (tid == 0)
        out[0] = (part[0] + part[1] + part[2] + part[3]) * (1.0f / (float)NN);
}

extern "C" void kernel_launch(void* const* d_in, const int* in_sizes, int n_in,
                              void* d_out, int out_size, void* d_ws, size_t ws_size,
                              hipStream_t stream) {
    const float* batch   = (const float*)d_in[0];
    const int*   anchors = (const int*)d_in[1];
    const int*   pos_idx = (const int*)d_in[2];
    const int*   neg_idx = (const int*)d_in[3];
    float*       wsf     = (float*)d_ws;
    float*       out     = (float*)d_out;

    half8* hb    = (half8*)wsf;
    float* norms = wsf + WS_NORM;
    float* res   = wsf + WS_RES;

    convert_kernel<<<NN / 4, 256, 0, stream>>>((const float4*)batch, hb, norms);
    dist_kernel<<<NN, 256, 0, stream>>>(hb, anchors, pos_idx, neg_idx, norms, res);
    reduce_kernel<<<1, 256, 0, stream>>>(res, out);
}

// Round 11
// 82.232 us; speedup vs baseline: 1.5059x; 1.0128x over previous
//
#include <hip/hip_runtime.h>
#include <hip/hip_fp8.h>
#include <math.h>
#include <float.h>

// Problem constants (from the reference)
#define NN 4096
#define DD 512
#define PP 8
#define QQ 32
#define NB_TOT 40
#define NPW 10                     // neighbors per wave (4 waves x 10 = 40)
constexpr float MARGIN = 1.0f;
constexpr float L2W    = 0.005f;
constexpr float EPS    = 1e-6f;

// ws layout (floats):
//   [0, NN*128)              fp8 batch copy (2 MB = NN*512 bytes)
//   [NN*128, +NN)            per-row fp32 norms
//   [NN*128+NN, +NN)         per-anchor results
#define WS_NORM (NN * 128)
#define WS_RES  (WS_NORM + NN)

__device__ inline float wave_reduce_sum(float v) {
    v += __shfl_xor(v, 32, 64);
    v += __shfl_xor(v, 16, 64);
    v += __shfl_xor(v,  8, 64);
    v += __shfl_xor(v,  4, 64);
    v += __shfl_xor(v,  2, 64);
    v += __shfl_xor(v,  1, 64);
    return v;
}

__device__ inline float wave_reduce_max(float v) {
    v = fmaxf(v, __shfl_xor(v, 32, 64));
    v = fmaxf(v, __shfl_xor(v, 16, 64));
    v = fmaxf(v, __shfl_xor(v,  8, 64));
    v = fmaxf(v, __shfl_xor(v,  4, 64));
    v = fmaxf(v, __shfl_xor(v,  2, 64));
    v = fmaxf(v, __shfl_xor(v,  1, 64));
    return v;
}

// half-wave (32-lane) butterfly sum: masks 16..1 stay within the half
__device__ inline float half_reduce_sum(float v) {
    v += __shfl_xor(v, 16, 64);
    v += __shfl_xor(v,  8, 64);
    v += __shfl_xor(v,  4, 64);
    v += __shfl_xor(v,  2, 64);
    v += __shfl_xor(v,  1, 64);
    return v;
}

// One wave per row: read 2KB fp32 (coalesced), write 512B fp8 (coalesced),
// and compute the exact fp32 row norm. 4 rows per 256-thread block.
__global__ __launch_bounds__(256) void convert_kernel(
    const float4* __restrict__ batch4,   // [NN*128]
    uint2*        __restrict__ fb,       // [NN*64] (8 fp8 bytes per elem)
    float*        __restrict__ norms)    // [NN]
{
    const int row  = blockIdx.x * 4 + (threadIdx.x >> 6);
    const int lane = threadIdx.x & 63;

    const float4 v0 = batch4[row * 128 + lane * 2];
    const float4 v1 = batch4[row * 128 + lane * 2 + 1];

    union { unsigned char b[8]; uint2 u; } pk;
    pk.b[0] = __hip_fp8_e4m3(v0.x).__x;
    pk.b[1] = __hip_fp8_e4m3(v0.y).__x;
    pk.b[2] = __hip_fp8_e4m3(v0.z).__x;
    pk.b[3] = __hip_fp8_e4m3(v0.w).__x;
    pk.b[4] = __hip_fp8_e4m3(v1.x).__x;
    pk.b[5] = __hip_fp8_e4m3(v1.y).__x;
    pk.b[6] = __hip_fp8_e4m3(v1.z).__x;
    pk.b[7] = __hip_fp8_e4m3(v1.w).__x;
    fb[row * 64 + lane] = pk.u;

    float s = v0.x*v0.x + v0.y*v0.y + v0.z*v0.z + v0.w*v0.w
            + v1.x*v1.x + v1.y*v1.y + v1.z*v1.z + v1.w*v1.w;
    s = wave_reduce_sum(s);
    if (lane == 0) norms[row] = sqrtf(s);
}

__device__ inline void decode16(const uint4 q, float* f) {
    union { uint4 u; unsigned char c[16]; } v; v.u = q;
    #pragma unroll
    for (int j = 0; j < 16; ++j) {
        __hip_fp8_e4m3 h; h.__x = v.c[j];
        f[j] = (float)h;
    }
}

// One block per anchor; 4 waves x 10 neighbors (R10 structure + fp8 pair
// loads). An fp8 row is 512 B, so ONE dwordx4 instruction per wave covers
// TWO rows (lanes 0-31 -> row 2t, lanes 32-63 -> row 2t+1): 5 pair-requests
// + 1 anchor per wave (was 11), and cache-line fills halve vs fp16 — wins
// under both the MSHR-line bound and the request-issue bound. Load cluster
// pinned by sched_barrier (R8/R9: compiler otherwise serializes gathers).
__global__ __launch_bounds__(256) void dist_kernel(
    const uint4* __restrict__ fb,        // fp8 batch, 32 uint4 per row
    const int*   __restrict__ anchors,
    const int*   __restrict__ pos_idx,
    const int*   __restrict__ neg_idx,
    const float* __restrict__ norms,
    float*       __restrict__ res)
{
    const int i    = blockIdx.x;
    const int tid  = threadIdx.x;
    const int lane = tid & 63;
    const int wave = tid >> 6;            // 0..3
    const int half = lane >> 5;           // 0: row 2t, 1: row 2t+1
    const int l32  = lane & 31;
    const int jb   = wave * NPW;

    __shared__ float dist[NB_TOT];

    // ---- anchor row: one request (both halves read the same 512 B) ----
    const int arow = anchors[i];
    const uint4 ahq = fb[(size_t)arow * 32 + l32];
    float a[16];
    decode16(ahq, a);
    #pragma unroll
    for (int k = 0; k < 16; ++k) a[k] += EPS;

    // ---- this wave's 10 neighbor indices ----
    int idxs[NPW];
    #pragma unroll
    for (int t = 0; t < NPW; ++t) {
        const int j = jb + t;
        idxs[t] = (j < PP) ? pos_idx[i * PP + j] : neg_idx[i * QQ + (j - PP)];
    }

    // ---- 5 pair-requests: each loads 2 full rows (one per half-wave) ----
    uint4 bq[5];
    #pragma unroll
    for (int t = 0; t < 5; ++t)
        bq[t] = fb[(size_t)idxs[2 * t + half] * 32 + l32];
    __builtin_amdgcn_sched_barrier(0);    // do not sink loads past this point

    // ---- squared distances in fp32 (16 elems/lane per row) ----
    float s[5];
    #pragma unroll
    for (int t = 0; t < 5; ++t) {
        float b[16];
        decode16(bq[t], b);
        float acc = 0.0f;
        #pragma unroll
        for (int k = 0; k < 16; ++k) {
            const float d = a[k] - b[k];
            acc = fmaf(d, d, acc);
        }
        s[t] = acc;
    }

    // ---- 5 independent half-wave butterflies (each half owns its row) ----
    #pragma unroll
    for (int t = 0; t < 5; ++t) s[t] = half_reduce_sum(s[t]);

    // ---- lanes 0 and 32 hold the two row sums of each pair ----
    #pragma unroll
    for (int t = 0; t < 5; ++t)
        if (l32 == 0) dist[jb + 2 * t + half] = sqrtf(s[t]);

    __syncthreads();

    // ---- wave-parallel logsumexp epilogue (lanes 0..39 of wave 0) ----
    if (wave == 0) {
        const float d = (lane < NB_TOT) ? dist[lane] : 0.0f;

        const bool pact = (lane < PP);
        const float pm = wave_reduce_max(pact ? d : -FLT_MAX);
        const float ps = wave_reduce_sum(pact ? expf(d - pm) : 0.0f);
        const float pos_term = pm + logf(ps);

        const bool nact = (lane >= PP) && (lane < NB_TOT);
        const float nv = MARGIN - d;
        const float nm = wave_reduce_max(nact ? nv : -FLT_MAX);
        const float ns = wave_reduce_sum(nact ? expf(nv - nm) : 0.0f);
        const float neg_term = nm + logf(ns);

        if (lane == 0)
            res[i] = fmaxf(0.0f, pos_term + neg_term) + L2W * norms[i];
    }
}

// Single-block final reduction: out = mean(res[0..N))
__global__ __launch_bounds__(256) void reduce_kernel(
    const float* __restrict__ res, float* __restrict__ out)
{
    const int tid  = threadIdx.x;
    const int lane = tid & 63;
    const int wave = tid >> 6;

    const float4* __restrict__ w4 = reinterpret_cast<const float4*>(res);
    float s = 0.0f;
    #pragma unroll
    for (int k = 0; k < 4; ++k) {          // 1024 float4 total
        const float4 v = w4[tid + 256 * k];
        s += v.x + v.y + v.z + v.w;
    }
    s = wave_reduce_sum(s);

    __shared__ float part[4];
    if (lane == 0) part[wave] = s;
    __syncthreads();
    if (tid == 0)
        out[0] = (part[0] + part[1] + part[2] + part[3]) * (1.0f / (float)NN);
}

extern "C" void kernel_launch(void* const* d_in, const int* in_sizes, int n_in,
                              void* d_out, int out_size, void* d_ws, size_t ws_size,
                              hipStream_t stream) {
    const float* batch   = (const float*)d_in[0];
    const int*   anchors = (const int*)d_in[1];
    const int*   pos_idx = (const int*)d_in[2];
    const int*   neg_idx = (const int*)d_in[3];
    float*       wsf     = (float*)d_ws;
    float*       out     = (float*)d_out;

    uint2* fb    = (uint2*)wsf;
    float* norms = wsf + WS_NORM;
    float* res   = wsf + WS_RES;

    convert_kernel<<<NN / 4, 256, 0, stream>>>((const float4*)batch, fb, norms);
    dist_kernel<<<NN, 256, 0, stream>>>((const uint4*)fb, anchors, pos_idx,
                                        neg_idx, norms, res);
    reduce_kernel<<<1, 256, 0, stream>>>(res, out);
}